// Round 6
// baseline (49.782 us; speedup 1.0000x reference)
//
#include <hip/hip_runtime.h>
#include <hip/hip_fp16.h>
#include <stdint.h>

// HashGridEncoder forward (Instant-NGP style), MI355X / gfx950.
// L=16 levels, T=2^15 entries/level, F=2 features, DIM=3.
//
// Structure (round 4): one block per (level, point-chunk); level's 32768-entry
// table slice staged in LDS as packed f16x2 (128KB), all gathers are LDS.
// bid = l*16 + c -> XCD = c%8 level-independent (kNC==16, multiple of 8):
// the 16 level-blocks of a chunk share an XCD so partial 8B writes per 128B
// out-line merge in L2 (WRITE_SIZE confirmed 62.5MB, no amplification).
//
// Round-6 change: round 5 showed the compiler sank the batched ds_reads next
// to their uses (VGPR stayed 52) -> serial LDS latency per item with only
// 4 waves/SIMD. Now a register double-buffered 1-point-deep software pipeline,
// pinned with sched_barrier(0): each phase issues 8 ds_reads for point i+1,
// prefetches x for i+2, then consumes point i. Compiler's counted lgkmcnt(8)
// preserves the overlap. Consume uses packed __hfma2 (halves consume VALU).
// f16-acc error <= ~1e-6; measured headroom 1.9e-6 vs threshold 7.8e-6.

constexpr int      kL  = 16;
constexpr int      kT  = 32768;           // 2^15
constexpr uint32_t kM  = kT - 1;
constexpr uint32_t kP1 = 2654435761u;
constexpr uint32_t kP2 = 805459861u;
constexpr int      kNC = 16;              // point chunks (multiple of 8!)
constexpr int      kBT = 1024;            // threads per block

typedef float f32x2 __attribute__((ext_vector_type(2)));

// scales[l] = 16 * 2^(l/3) - 1  (B = 2^(1/3) exactly), f64-rounded to f32.
__device__ __constant__ float c_scales[kL] = {
    15.0f,
    19.158736798317972f,
    24.398416831491190f,
    31.0f,
    39.317473596635944f,
    49.796833662982380f,
    63.0f,
    79.634947193271890f,
    100.59366732596477f,
    127.0f,
    160.26989438654378f,
    202.18733465192953f,
    255.0f,
    321.53978877308750f,
    405.37466930385903f,
    511.0f
};

__device__ __forceinline__ void load3(float (&v)[3], const float* __restrict__ x, int n) {
    v[0] = x[n * 3 + 0];
    v[1] = x[n * 3 + 1];
    v[2] = x[n * 3 + 2];
}

// hash the point, compute the 8 corner weights, and ISSUE the 8 LDS reads.
__device__ __forceinline__ void issue8(
    const uint32_t* __restrict__ ltab, float s, const float (&xv)[3],
    uint32_t (&buf)[8], float (&w)[8])
{
    float p0 = fmaf((xv[0] + 1.0f) * 0.5f, s, 0.5f);
    float p1 = fmaf((xv[1] + 1.0f) * 0.5f, s, 0.5f);
    float p2 = fmaf((xv[2] + 1.0f) * 0.5f, s, 0.5f);

    float fl0 = floorf(p0), fl1 = floorf(p1), fl2 = floorf(p2);
    float fr0 = p0 - fl0,   fr1 = p1 - fl1,   fr2 = p2 - fl2;

    uint32_t g0 = (uint32_t)(int)fl0;
    uint32_t g1 = (uint32_t)(int)fl1;
    uint32_t g2 = (uint32_t)(int)fl2;

    uint32_t hx0 = g0;        uint32_t hx1 = g0 + 1u;
    uint32_t hy0 = g1 * kP1;  uint32_t hy1 = hy0 + kP1;
    uint32_t hz0 = g2 * kP2;  uint32_t hz1 = hz0 + kP2;

    float wy0 = 1.0f - fr1, wz0 = 1.0f - fr2;
    float wx0 = 1.0f - fr0;

    uint32_t hyz[4];
    float    wyz[4];
    hyz[0] = hy0 ^ hz0;  wyz[0] = wy0 * wz0;
    hyz[1] = hy1 ^ hz0;  wyz[1] = fr1 * wz0;
    hyz[2] = hy0 ^ hz1;  wyz[2] = wy0 * fr2;
    hyz[3] = hy1 ^ hz1;  wyz[3] = fr1 * fr2;

#pragma unroll
    for (int cc = 0; cc < 8; ++cc) {
        uint32_t hx = (cc & 1) ? hx1 : hx0;
        uint32_t idx = (hx ^ hyz[cc >> 1]) & kM;
        w[cc]   = ((cc & 1) ? fr0 : wx0) * wyz[cc >> 1];
        buf[cc] = ltab[idx];
    }
}

__device__ __forceinline__ f32x2 consume8(const uint32_t (&buf)[8], const float (&w)[8]) {
    __half2 acc = __float2half2_rn(0.0f);
#pragma unroll
    for (int cc = 0; cc < 8; ++cc) {
        __half2 h = *reinterpret_cast<const __half2*>(&buf[cc]);
        acc = __hfma2(__float2half2_rn(w[cc]), h, acc);
    }
    f32x2 r;
    r.x = __low2float(acc);
    r.y = __high2float(acc);
    return r;
}

__global__ __launch_bounds__(kBT, 4) void hashgrid_fwd(
    const float*  __restrict__ x,      // (N,3)
    const float2* __restrict__ table,  // (L,T) of float2
    f32x2*        __restrict__ out,    // (N,L) of float2
    int n_points, int chunk_sz)
{
    __shared__ uint32_t ltab[kT];      // 128 KB: level slice as packed f16x2

    int bid = blockIdx.x;
    int l   = bid >> 4;                // bid = l*16 + c  -> XCD = c%8
    int c   = bid & 15;

    // ---- stage level slice: 32768 f32x2 -> packed f16x2 (float4 loads) ----
    const float4* tsrc4 = reinterpret_cast<const float4*>(table + (size_t)l * kT);
    for (int e = threadIdx.x; e < kT / 2; e += kBT) {
        float4 q = tsrc4[e];
        uint2 pp;
        pp.x = ((uint32_t)__half_as_ushort(__float2half_rn(q.y)) << 16)
             |  (uint32_t)__half_as_ushort(__float2half_rn(q.x));
        pp.y = ((uint32_t)__half_as_ushort(__float2half_rn(q.w)) << 16)
             |  (uint32_t)__half_as_ushort(__float2half_rn(q.z));
        *reinterpret_cast<uint2*>(&ltab[e * 2]) = pp;
    }
    __syncthreads();

    float s    = c_scales[l];
    int   base = c * chunk_sz;
    int   lim  = min(base + chunk_sz, n_points);
    int   nmax = lim - 1;
    // iters is uniform across the whole grid (all chunks are size 31250)
    int   iters = (chunk_sz + kBT - 1) / kBT;     // 31

    uint32_t bufA[8], bufB[8];
    float    wA[8],  wB[8];
    float    xA[3],  xB[3];

    int nA = base + (int)threadIdx.x;             // point of phase `it`
    load3(xA, x, min(nA, nmax));
    load3(xB, x, min(nA + kBT, nmax));

    issue8(ltab, s, xA, bufA, wA);                // issue phase 0
    __builtin_amdgcn_sched_barrier(0);

    for (int it = 0; it < iters; it += 2) {
        // ---- phase A: issue B(it+1), prefetch x(it+2), consume A(it) ----
        if (it + 1 < iters) issue8(ltab, s, xB, bufB, wB);
        load3(xA, x, min(nA + 2 * kBT, nmax));    // x for phase it+2
        __builtin_amdgcn_sched_barrier(0);
        {
            f32x2 r = consume8(bufA, wA);
            if (nA < lim) out[(size_t)nA * kL + l] = r;
        }
        // ---- phase B: issue A(it+2), prefetch x(it+3), consume B(it+1) ----
        if (it + 2 < iters) issue8(ltab, s, xA, bufA, wA);
        load3(xB, x, min(nA + 3 * kBT, nmax));    // x for phase it+3
        __builtin_amdgcn_sched_barrier(0);
        if (it + 1 < iters) {
            f32x2 r = consume8(bufB, wB);
            int nB = nA + kBT;
            if (nB < lim) out[(size_t)nB * kL + l] = r;
        }
        nA += 2 * kBT;
    }
}

extern "C" void kernel_launch(void* const* d_in, const int* in_sizes, int n_in,
                              void* d_out, int out_size, void* d_ws, size_t ws_size,
                              hipStream_t stream) {
    const float*  x     = (const float*)d_in[0];
    const float2* table = (const float2*)d_in[1];
    f32x2*        out   = (f32x2*)d_out;

    int n_points = in_sizes[0] / 3;                  // (N,3) flat
    int chunk_sz = (n_points + kNC - 1) / kNC;       // 31250 for N=500000
    int blocks   = kL * kNC;                         // 256 = 1 per CU

    hashgrid_fwd<<<blocks, kBT, 0, stream>>>(x, table, out, n_points, chunk_sz);
}

// Round 7
// 49.776 us; speedup vs baseline: 1.0001x; 1.0001x over previous
//
#include <hip/hip_runtime.h>
#include <hip/hip_fp16.h>
#include <stdint.h>

// HashGridEncoder forward (Instant-NGP style), MI355X / gfx950.
// L=16 levels, T=2^15 entries/level, F=2 features, DIM=3.
//
// Structure (round 4): one block per (level, point-chunk); level's 32768-entry
// table slice staged in LDS as packed f16x2 (128KB), all gathers are LDS.
// bid = l*16 + c -> XCD = c%8: the 16 level-blocks of a chunk share an XCD so
// partial 8B writes per 128B out-line merge in L2 (WRITE_SIZE = 62.5MB, no
// amplification).
//
// Round-7: rounds 5/6 pipelines were collapsed by the compiler (VGPR stuck at
// 52 = loads sunk to uses -> serial LDS latency at 4 waves/SIMD). Now a
// within-iteration split, fence-enforced:
//   [hash + issue 16 ds_reads for 2 points] -> sched_barrier(0) ->
//   [x prefetch + ALL weight math (~120cyc VALU, no dependence on loads)] ->
//   [consume: compiler emits counted lgkmcnt]
// Main 30 iterations carry no bounds checks (tail split off). If this works,
// VGPR must rise to ~70-90.

constexpr int      kL  = 16;
constexpr int      kT  = 32768;           // 2^15
constexpr uint32_t kM  = kT - 1;
constexpr uint32_t kP1 = 2654435761u;
constexpr uint32_t kP2 = 805459861u;
constexpr int      kNC = 16;              // point chunks (multiple of 8)
constexpr int      kBT = 1024;            // threads per block

typedef float f32x2 __attribute__((ext_vector_type(2)));

// scales[l] = 16 * 2^(l/3) - 1  (B = 2^(1/3) exactly), f64-rounded to f32.
__device__ __constant__ float c_scales[kL] = {
    15.0f,
    19.158736798317972f,
    24.398416831491190f,
    31.0f,
    39.317473596635944f,
    49.796833662982380f,
    63.0f,
    79.634947193271890f,
    100.59366732596477f,
    127.0f,
    160.26989438654378f,
    202.18733465192953f,
    255.0f,
    321.53978877308750f,
    405.37466930385903f,
    511.0f
};

__device__ __forceinline__ void load3(float (&v)[3], const float* __restrict__ x, int n) {
    v[0] = x[n * 3 + 0];
    v[1] = x[n * 3 + 1];
    v[2] = x[n * 3 + 2];
}

// hash the point and ISSUE the 8 LDS reads; only fr[] is kept for weights.
__device__ __forceinline__ void hash_issue(
    const uint32_t* __restrict__ ltab, float s, const float (&xv)[3],
    float (&fr)[3], uint32_t (&buf)[8])
{
    float p0 = fmaf((xv[0] + 1.0f) * 0.5f, s, 0.5f);
    float p1 = fmaf((xv[1] + 1.0f) * 0.5f, s, 0.5f);
    float p2 = fmaf((xv[2] + 1.0f) * 0.5f, s, 0.5f);

    float fl0 = floorf(p0), fl1 = floorf(p1), fl2 = floorf(p2);
    fr[0] = p0 - fl0;  fr[1] = p1 - fl1;  fr[2] = p2 - fl2;

    uint32_t g0 = (uint32_t)(int)fl0;
    uint32_t g1 = (uint32_t)(int)fl1;
    uint32_t g2 = (uint32_t)(int)fl2;

    uint32_t g0p = g0 + 1u;
    uint32_t hy0 = g1 * kP1;  uint32_t hy1 = hy0 + kP1;
    uint32_t hz0 = g2 * kP2;  uint32_t hz1 = hz0 + kP2;

    uint32_t hyz0 = hy0 ^ hz0;
    uint32_t hyz1 = hy1 ^ hz0;
    uint32_t hyz2 = hy0 ^ hz1;
    uint32_t hyz3 = hy1 ^ hz1;

    buf[0] = ltab[(g0  ^ hyz0) & kM];
    buf[1] = ltab[(g0p ^ hyz0) & kM];
    buf[2] = ltab[(g0  ^ hyz1) & kM];
    buf[3] = ltab[(g0p ^ hyz1) & kM];
    buf[4] = ltab[(g0  ^ hyz2) & kM];
    buf[5] = ltab[(g0p ^ hyz2) & kM];
    buf[6] = ltab[(g0  ^ hyz3) & kM];
    buf[7] = ltab[(g0p ^ hyz3) & kM];
}

// weight math (independent of the loads) + consume.
__device__ __forceinline__ f32x2 wconsume(const float (&fr)[3], const uint32_t (&buf)[8]) {
    float wx0 = 1.0f - fr[0];
    float wy0 = 1.0f - fr[1];
    float wz0 = 1.0f - fr[2];
    float wyz0 = wy0  * wz0;
    float wyz1 = fr[1] * wz0;
    float wyz2 = wy0  * fr[2];
    float wyz3 = fr[1] * fr[2];

    float wf[8];
    wf[0] = wx0   * wyz0;  wf[1] = fr[0] * wyz0;
    wf[2] = wx0   * wyz1;  wf[3] = fr[0] * wyz1;
    wf[4] = wx0   * wyz2;  wf[5] = fr[0] * wyz2;
    wf[6] = wx0   * wyz3;  wf[7] = fr[0] * wyz3;

    __half2 acc = __float2half2_rn(0.0f);
#pragma unroll
    for (int cc = 0; cc < 8; ++cc) {
        __half2 h = *reinterpret_cast<const __half2*>(&buf[cc]);
        acc = __hfma2(__float2half2_rn(wf[cc]), h, acc);
    }
    f32x2 r;
    r.x = __low2float(acc);
    r.y = __high2float(acc);
    return r;
}

__global__ __launch_bounds__(kBT, 4) void hashgrid_fwd(
    const float*  __restrict__ x,      // (N,3)
    const float2* __restrict__ table,  // (L,T) of float2
    f32x2*        __restrict__ out,    // (N,L) of float2
    int n_points, int chunk_sz)
{
    __shared__ uint32_t ltab[kT];      // 128 KB: level slice as packed f16x2

    int bid = blockIdx.x;
    int l   = bid >> 4;                // bid = l*16 + c  -> XCD = c%8
    int c   = bid & 15;

    // ---- stage level slice: 32768 f32x2 -> packed f16x2 (float4 loads) ----
    const float4* tsrc4 = reinterpret_cast<const float4*>(table + (size_t)l * kT);
    for (int e = threadIdx.x; e < kT / 2; e += kBT) {
        float4 q = tsrc4[e];
        uint2 pp;
        pp.x = ((uint32_t)__half_as_ushort(__float2half_rn(q.y)) << 16)
             |  (uint32_t)__half_as_ushort(__float2half_rn(q.x));
        pp.y = ((uint32_t)__half_as_ushort(__float2half_rn(q.w)) << 16)
             |  (uint32_t)__half_as_ushort(__float2half_rn(q.z));
        *reinterpret_cast<uint2*>(&ltab[e * 2]) = pp;
    }
    __syncthreads();

    float s    = c_scales[l];
    int   tid  = (int)threadIdx.x;
    int   base = c * chunk_sz;
    int   lim  = min(base + chunk_sz, n_points);

    // main iterations with NO bounds checks: it in [0, unguarded)
    int unguarded = (chunk_sz / kBT) & ~1;        // 30 for chunk_sz=31250

    int n = base + tid;
    float xc0[3], xc1[3];
    load3(xc0, x, n);
    load3(xc1, x, n + kBT);

    for (int it = 0; it < unguarded; it += 2) {
        float    fr0[3], fr1[3];
        uint32_t b0[8],  b1[8];

        // ---- phase 1: hash + issue all 16 LDS reads ----
        hash_issue(ltab, s, xc0, fr0, b0);
        hash_issue(ltab, s, xc1, fr1, b1);
        __builtin_amdgcn_sched_barrier(0);

        // ---- phase 2: x prefetch + weight math (covers LDS latency) ----
        bool last = (it + 2 >= unguarded);
        int  np0  = last ? n : n + 2 * kBT;       // stay in-chunk, always valid
        int  np1  = last ? n : n + 3 * kBT;
        float xn0[3], xn1[3];
        load3(xn0, x, np0);
        load3(xn1, x, np1);

        // ---- phase 3: consume (counted lgkmcnt) + store ----
        f32x2 r0 = wconsume(fr0, b0);
        out[(size_t)n * kL + l] = r0;
        f32x2 r1 = wconsume(fr1, b1);
        out[(size_t)(n + kBT) * kL + l] = r1;

#pragma unroll
        for (int k = 0; k < 3; ++k) { xc0[k] = xn0[k]; xc1[k] = xn1[k]; }
        n += 2 * kBT;
    }

    // guarded tail (1 iteration for chunk_sz=31250)
    for (int nG = base + tid + unguarded * kBT; nG < lim; nG += kBT) {
        float xv[3];
        load3(xv, x, nG);
        float fr[3]; uint32_t b[8];
        hash_issue(ltab, s, xv, fr, b);
        f32x2 r = wconsume(fr, b);
        out[(size_t)nG * kL + l] = r;
    }
}

extern "C" void kernel_launch(void* const* d_in, const int* in_sizes, int n_in,
                              void* d_out, int out_size, void* d_ws, size_t ws_size,
                              hipStream_t stream) {
    const float*  x     = (const float*)d_in[0];
    const float2* table = (const float2*)d_in[1];
    f32x2*        out   = (f32x2*)d_out;

    int n_points = in_sizes[0] / 3;                  // (N,3) flat
    int chunk_sz = (n_points + kNC - 1) / kNC;       // 31250 for N=500000
    int blocks   = kL * kNC;                         // 256 = 1 per CU

    hashgrid_fwd<<<blocks, kBT, 0, stream>>>(x, table, out, n_points, chunk_sz);
}